// Round 3
// baseline (534.999 us; speedup 1.0000x reference)
//
#include <hip/hip_runtime.h>
#include <cstdint>
#include <cmath>

// ---------------------------------------------------------------------------
// VGAE-style GCN forward, CSR-gather formulation (no feature-wide atomics):
//   deg(int) -> offs (1-block scan) -> CSR fill ->
//   gemm1: A = (x@W1)*dis, B = (x@W1)*dis^2
//   gather<RELU>: agg1 = B + dis*sum A[src]; h=relu(agg1+b1); A=h*dis, B=h*dis^2
//   gather<PLAIN>: B = B + dis*sum A[src]     (B = hagg)
//   pool: block-per-graph (batch sorted -> binary search), zero atomics
//   final: pooled mean algebra + FC + log_softmax
// Aggregation hoisted before W3/W4 (linearity); mean never materialized.
// ---------------------------------------------------------------------------

__global__ __launch_bounds__(256) void deg_kernel(const int* __restrict__ dst,
                                                  int* __restrict__ deg, int E) {
    int e = blockIdx.x * 256 + threadIdx.x;
    if (e < E) atomicAdd(&deg[dst[e]], 1);
}

__global__ __launch_bounds__(256) void dis_kernel(const int* __restrict__ deg,
                                                  float* __restrict__ dis, int N) {
    int i = blockIdx.x * 256 + threadIdx.x;
    if (i < N) dis[i] = rsqrtf((float)deg[i] + 1.0f);
}

// Exclusive scan of deg[0..N) -> offs[0..N]; single block of 1024 threads.
__global__ __launch_bounds__(1024) void scan_kernel(const int* __restrict__ deg,
                                                    int* __restrict__ offs, int N) {
    __shared__ int sums[1024];
    int t = threadIdx.x;
    int C = (N + 1023) / 1024;
    int beg = t * C;
    int end = min(beg + C, N);
    int s = 0;
    for (int i = beg; i < end; i++) s += deg[i];
    sums[t] = s;
    __syncthreads();
    for (int off = 1; off < 1024; off <<= 1) {
        int v = (t >= off) ? sums[t - off] : 0;
        __syncthreads();
        sums[t] += v;
        __syncthreads();
    }
    int run = (t == 0) ? 0 : sums[t - 1];
    for (int i = beg; i < end; i++) { offs[i] = run; run += deg[i]; }
    if (t == 1023) offs[N] = run;   // == E
}

__global__ __launch_bounds__(256) void fill_kernel(const int* __restrict__ src,
                                                   const int* __restrict__ dst,
                                                   const int* __restrict__ offs,
                                                   int* __restrict__ cursor,
                                                   int* __restrict__ adj, int E) {
    int e = blockIdx.x * 256 + threadIdx.x;
    if (e >= E) return;
    int d = dst[e];
    int pos = offs[d] + atomicAdd(&cursor[d], 1);
    adj[pos] = src[e];
}

// h0 = x @ W1  (M=N, N=128, K=256), f32. Epilogue: A = h0*dis, B = h0*dis^2.
// Thread tx owns cols {tx*4..tx*4+3} and {64+tx*4..64+tx*4+3}  (2-way LDS alias, free)
__global__ __launch_bounds__(256) void gemm1_kernel(const float* __restrict__ x,
                                                    const float* __restrict__ W,
                                                    const float* __restrict__ dis,
                                                    float* __restrict__ A,
                                                    float* __restrict__ B, int N) {
    __shared__ float xs[64][68];   // 64 rows x 64 k (pad for f4 stores)
    __shared__ float ws[64][128];  // 64 k x 128 cols
    int tid = threadIdx.x;
    int tx = tid & 15;
    int ty = tid >> 4;   // row group: rows ty*4 .. ty*4+3
    int rowBase = blockIdx.x * 64;

    float acc[4][8];
#pragma unroll
    for (int i = 0; i < 4; i++)
#pragma unroll
        for (int j = 0; j < 8; j++) acc[i][j] = 0.f;

    for (int k0 = 0; k0 < 256; k0 += 64) {
#pragma unroll
        for (int i = 0; i < 4; i++) {
            int u = tid + i * 256;     // float4 unit 0..1023
            int r = u >> 4;
            int c = u & 15;
            float4 v = make_float4(0.f, 0.f, 0.f, 0.f);
            int row = rowBase + r;
            if (row < N) v = *(const float4*)(x + (size_t)row * 256 + k0 + c * 4);
            *(float4*)&xs[r][c * 4] = v;
        }
#pragma unroll
        for (int i = 0; i < 8; i++) {
            int u = tid + i * 256;     // 0..2047
            int r = u >> 5;
            int c = u & 31;
            *(float4*)&ws[r][c * 4] = *(const float4*)(W + (size_t)(k0 + r) * 128 + c * 4);
        }
        __syncthreads();
#pragma unroll
        for (int k = 0; k < 64; k++) {
            float xv[4];
#pragma unroll
            for (int i = 0; i < 4; i++) xv[i] = xs[ty * 4 + i][k];
            float4 w0 = *(float4*)&ws[k][tx * 4];
            float4 w1 = *(float4*)&ws[k][64 + tx * 4];
            float wv[8] = {w0.x, w0.y, w0.z, w0.w, w1.x, w1.y, w1.z, w1.w};
#pragma unroll
            for (int i = 0; i < 4; i++)
#pragma unroll
                for (int j = 0; j < 8; j++) acc[i][j] = fmaf(xv[i], wv[j], acc[i][j]);
        }
        __syncthreads();
    }
#pragma unroll
    for (int i = 0; i < 4; i++) {
        int row = rowBase + ty * 4 + i;
        if (row >= N) continue;
        float dv = dis[row];
        float d2 = dv * dv;
#pragma unroll
        for (int half = 0; half < 2; half++) {
            int colBase = half * 64 + tx * 4;
            float4 v = make_float4(acc[i][half * 4], acc[i][half * 4 + 1],
                                   acc[i][half * 4 + 2], acc[i][half * 4 + 3]);
            float4 a = make_float4(v.x * dv, v.y * dv, v.z * dv, v.w * dv);
            float4 b = make_float4(v.x * d2, v.y * d2, v.z * d2, v.w * d2);
            *(float4*)(A + (size_t)row * 128 + colBase) = a;
            *(float4*)(B + (size_t)row * 128 + colBase) = b;
        }
    }
}

// One wave per dst node. a = sum_{e in in(node)} Ain[src_e] (float2/lane).
// MODE 0: B[node] += dis[node]*a
// MODE 1: v = relu(B[node] + dis[node]*a + b1); A[node] = v*dis; B[node] = v*dis^2
template <int MODE>
__global__ __launch_bounds__(256) void gather_kernel(const int* __restrict__ offs,
                                                     const int* __restrict__ adj,
                                                     const float* __restrict__ dis,
                                                     const float* __restrict__ b1,
                                                     const float* __restrict__ Ain,
                                                     float* __restrict__ Aout,
                                                     float* __restrict__ B, int N) {
    int lane = threadIdx.x & 63;
    int node = blockIdx.x * 4 + (threadIdx.x >> 6);
    if (node >= N) return;
    int beg = offs[node];
    int end = offs[node + 1];
    float2 a = make_float2(0.f, 0.f);
    int e = beg;
    for (; e + 3 < end; e += 4) {
        int s0 = adj[e], s1 = adj[e + 1], s2 = adj[e + 2], s3 = adj[e + 3];
        float2 v0 = ((const float2*)(Ain + (size_t)s0 * 128))[lane];
        float2 v1 = ((const float2*)(Ain + (size_t)s1 * 128))[lane];
        float2 v2 = ((const float2*)(Ain + (size_t)s2 * 128))[lane];
        float2 v3 = ((const float2*)(Ain + (size_t)s3 * 128))[lane];
        a.x += v0.x + v1.x + v2.x + v3.x;
        a.y += v0.y + v1.y + v2.y + v3.y;
    }
    for (; e < end; e++) {
        int s = adj[e];
        float2 v = ((const float2*)(Ain + (size_t)s * 128))[lane];
        a.x += v.x;
        a.y += v.y;
    }
    float dd = dis[node];
    float2* bp = (float2*)(B + (size_t)node * 128) + lane;
    float2 cur = *bp;
    if (MODE == 0) {
        cur.x += dd * a.x;
        cur.y += dd * a.y;
        *bp = cur;
    } else {
        float2 bb = ((const float2*)b1)[lane];
        float vx = fmaxf(cur.x + dd * a.x + bb.x, 0.f);
        float vy = fmaxf(cur.y + dd * a.y + bb.y, 0.f);
        float2* ap = (float2*)(Aout + (size_t)node * 128) + lane;
        *ap = make_float2(vx * dd, vy * dd);
        *bp = make_float2(vx * dd * dd, vy * dd * dd);
    }
}

// Block per graph (batch sorted). 4 waves split the node range; zero atomics.
// pooledT[g] = sum noise*exp(hagg@W4+b4); pooledH[g] = sum hagg; counts[g] = #nodes.
__global__ __launch_bounds__(256) void pool_kernel(const float* __restrict__ hagg,
                                                   const float* __restrict__ W4,
                                                   const float* __restrict__ b4,
                                                   const float* __restrict__ noise,
                                                   const int* __restrict__ batch,
                                                   float* __restrict__ pooledH,
                                                   float* __restrict__ pooledT,
                                                   float* __restrict__ counts, int N) {
    __shared__ float w4s[128 * 64];
    __shared__ float sT[4][64];
    __shared__ float sH[4][128];
    int g = blockIdx.x;
    int tid = threadIdx.x;
    for (int i = tid; i < 128 * 64; i += 256) w4s[i] = W4[i];
    // binary search for [lo, hi) of graph g in sorted batch
    int lo, hi;
    {
        int l = 0, r = N;
        while (l < r) { int m = (l + r) >> 1; if (batch[m] < g) l = m + 1; else r = m; }
        lo = l;
        r = N;
        while (l < r) { int m = (l + r) >> 1; if (batch[m] < g + 1) l = m + 1; else r = m; }
        hi = l;
    }
    __syncthreads();
    int lane = tid & 63;
    int wv = tid >> 6;
    float accT = 0.f;
    float2 accH = make_float2(0.f, 0.f);
    float bv = b4[lane];
    for (int node = lo + wv; node < hi; node += 4) {
        const float* hrow = hagg + (size_t)node * 128;
        float acc = bv;
#pragma unroll
        for (int k = 0; k < 128; k++) acc = fmaf(hrow[k], w4s[k * 64 + lane], acc);
        accT += noise[(size_t)node * 64 + lane] * expf(acc);
        float2 hv = ((const float2*)hrow)[lane];
        accH.x += hv.x;
        accH.y += hv.y;
    }
    sT[wv][lane] = accT;
    sH[wv][lane * 2] = accH.x;
    sH[wv][lane * 2 + 1] = accH.y;
    __syncthreads();
    if (tid < 64) {
        pooledT[g * 64 + tid] = sT[0][tid] + sT[1][tid] + sT[2][tid] + sT[3][tid];
    } else if (tid < 192) {
        int f = tid - 64;
        pooledH[g * 128 + f] = sH[0][f] + sH[1][f] + sH[2][f] + sH[3][f];
    } else if (tid == 192) {
        counts[g] = (float)(hi - lo);
    }
}

// pooled = (pooledH@W3 + cnt*b3 + pooledT)/max(cnt,1); logits = pooled@Wfc + bfc; log_softmax
__global__ __launch_bounds__(64) void final_kernel(const float* __restrict__ pooledH,
                                                   const float* __restrict__ pooledT,
                                                   const float* __restrict__ counts,
                                                   const float* __restrict__ W3,
                                                   const float* __restrict__ b3,
                                                   const float* __restrict__ Wfc,
                                                   const float* __restrict__ bfc,
                                                   float* __restrict__ out) {
    int g = blockIdx.x;
    int f = threadIdx.x;  // 0..63
    float cnt = counts[g];
    float denom = fmaxf(cnt, 1.0f);
    float p = pooledT[g * 64 + f] + cnt * b3[f];
    const float* ph = pooledH + g * 128;
#pragma unroll
    for (int k = 0; k < 128; k++) p = fmaf(ph[k], W3[k * 64 + f], p);
    p /= denom;
    __shared__ float pl[64];
    __shared__ float lg[4];
    pl[f] = p;
    __syncthreads();
    if (f < 4) {
        float l = bfc[f];
#pragma unroll
        for (int k = 0; k < 64; k++) l = fmaf(pl[k], Wfc[k * 4 + f], l);
        lg[f] = l;
    }
    __syncthreads();
    if (f == 0) {
        float m = fmaxf(fmaxf(lg[0], lg[1]), fmaxf(lg[2], lg[3]));
        float s = expf(lg[0] - m) + expf(lg[1] - m) + expf(lg[2] - m) + expf(lg[3] - m);
        float lse = logf(s);
#pragma unroll
        for (int j = 0; j < 4; j++) out[g * 4 + j] = lg[j] - m - lse;
    }
}

extern "C" void kernel_launch(void* const* d_in, const int* in_sizes, int n_in,
                              void* d_out, int out_size, void* d_ws, size_t ws_size,
                              hipStream_t stream) {
    const float* x     = (const float*)d_in[0];
    const int*   ei    = (const int*)d_in[1];
    const int*   batch = (const int*)d_in[2];
    const float* W1    = (const float*)d_in[3];
    const float* b1    = (const float*)d_in[4];
    const float* W3    = (const float*)d_in[5];
    const float* b3    = (const float*)d_in[6];
    const float* W4    = (const float*)d_in[7];
    const float* b4    = (const float*)d_in[8];
    const float* Wfc   = (const float*)d_in[9];
    const float* bfc   = (const float*)d_in[10];
    const float* noise = (const float*)d_in[11];
    float* out = (float*)d_out;

    int N = in_sizes[0] / 256;
    int E = in_sizes[1] / 2;
    const int* src = ei;
    const int* dst = ei + E;

    // Workspace layout (floats first, then ints)
    float* A       = (float*)d_ws;                 // h0*dis, later h*dis      [N*128]
    float* B       = A + (size_t)N * 128;          // agg accumulators         [N*128]
    float* dis     = B + (size_t)N * 128;          // [N]
    float* pooledH = dis + N;                      // [512*128]
    float* pooledT = pooledH + 512 * 128;          // [512*64]
    float* counts  = pooledT + 512 * 64;           // [512]
    int*   degi    = (int*)(counts + 512);         // [N]
    int*   offs    = degi + N;                     // [N+1]
    int*   cursor  = offs + N + 1;                 // [N]
    int*   adj     = cursor + N;                   // [E]

    hipMemsetAsync(degi, 0, (size_t)N * sizeof(int), stream);
    hipMemsetAsync(cursor, 0, (size_t)N * sizeof(int), stream);

    // CSR build
    deg_kernel<<<(E + 255) / 256, 256, 0, stream>>>(dst, degi, E);
    dis_kernel<<<(N + 255) / 256, 256, 0, stream>>>(degi, dis, N);
    scan_kernel<<<1, 1024, 0, stream>>>(degi, offs, N);
    fill_kernel<<<(E + 255) / 256, 256, 0, stream>>>(src, dst, offs, cursor, adj, E);

    // Layer 1 GEMM: A = (x@W1)*dis, B = (x@W1)*dis^2
    gemm1_kernel<<<(N + 63) / 64, 256, 0, stream>>>(x, W1, dis, A, B, N);

    // gather1 + fused relu/bias/rescale: A = h*dis, B = h*dis^2
    gather_kernel<1><<<(N + 3) / 4, 256, 0, stream>>>(offs, adj, dis, b1, A, A, B, N);

    // gather2: B = hagg
    gather_kernel<0><<<(N + 3) / 4, 256, 0, stream>>>(offs, adj, dis, b1, A, A, B, N);

    // pooling (block per graph, batch sorted)
    pool_kernel<<<512, 256, 0, stream>>>(B, W4, b4, noise, batch, pooledH, pooledT, counts, N);

    final_kernel<<<512, 64, 0, stream>>>(pooledH, pooledT, counts, W3, b3, Wfc, bfc, out);
}

// Round 4
// 499.755 us; speedup vs baseline: 1.0705x; 1.0705x over previous
//
#include <hip/hip_runtime.h>
#include <cstdint>
#include <cmath>

// ---------------------------------------------------------------------------
// VGAE-style GCN forward, CSR-gather formulation:
//   deg(int) -> offs (1-block scan) -> CSR fill ->
//   gemm1: A = (x@W1)*dis, B = (x@W1)*dis^2
//   gather<RELU>: h=relu(B + dis*sum A[src] + b1); A=h*dis, B=h*dis^2
//   gather<PLAIN>: B = B + dis*sum A[src]     (B = hagg)
//   pool2: GEMM-tiled  T=noise*exp(hagg@W4+b4), segment-reduced by sorted batch
//   final: counts via binary search + pooled mean algebra + FC + log_softmax
// ---------------------------------------------------------------------------

__global__ __launch_bounds__(256) void deg_kernel(const int* __restrict__ dst,
                                                  int* __restrict__ deg, int E) {
    int e = blockIdx.x * 256 + threadIdx.x;
    if (e < E) atomicAdd(&deg[dst[e]], 1);
}

__global__ __launch_bounds__(256) void dis_kernel(const int* __restrict__ deg,
                                                  float* __restrict__ dis, int N) {
    int i = blockIdx.x * 256 + threadIdx.x;
    if (i < N) dis[i] = rsqrtf((float)deg[i] + 1.0f);
}

// Exclusive scan of deg[0..N) -> offs[0..N]; single block of 1024 threads.
__global__ __launch_bounds__(1024) void scan_kernel(const int* __restrict__ deg,
                                                    int* __restrict__ offs, int N) {
    __shared__ int sums[1024];
    int t = threadIdx.x;
    int C = (N + 1023) / 1024;
    int beg = t * C;
    int end = min(beg + C, N);
    int s = 0;
    for (int i = beg; i < end; i++) s += deg[i];
    sums[t] = s;
    __syncthreads();
    for (int off = 1; off < 1024; off <<= 1) {
        int v = (t >= off) ? sums[t - off] : 0;
        __syncthreads();
        sums[t] += v;
        __syncthreads();
    }
    int run = (t == 0) ? 0 : sums[t - 1];
    for (int i = beg; i < end; i++) { offs[i] = run; run += deg[i]; }
    if (t == 1023) offs[N] = run;   // == E
}

// cursor pre-initialized to offs (d2d copy); adj[pos] = src
__global__ __launch_bounds__(256) void fill_kernel(const int* __restrict__ src,
                                                   const int* __restrict__ dst,
                                                   int* __restrict__ cursor,
                                                   int* __restrict__ adj, int E) {
    int e = blockIdx.x * 256 + threadIdx.x;
    if (e >= E) return;
    int pos = atomicAdd(&cursor[dst[e]], 1);
    adj[pos] = src[e];
}

// h0 = x @ W1  (M=N, N=128, K=256), f32. Epilogue: A = h0*dis, B = h0*dis^2.
__global__ __launch_bounds__(256) void gemm1_kernel(const float* __restrict__ x,
                                                    const float* __restrict__ W,
                                                    const float* __restrict__ dis,
                                                    float* __restrict__ A,
                                                    float* __restrict__ B, int N) {
    __shared__ float xs[64][68];   // 64 rows x 64 k (pad for f4 stores)
    __shared__ float ws[64][128];  // 64 k x 128 cols
    int tid = threadIdx.x;
    int tx = tid & 15;
    int ty = tid >> 4;   // row group: rows ty*4 .. ty*4+3
    int rowBase = blockIdx.x * 64;

    float acc[4][8];
#pragma unroll
    for (int i = 0; i < 4; i++)
#pragma unroll
        for (int j = 0; j < 8; j++) acc[i][j] = 0.f;

    for (int k0 = 0; k0 < 256; k0 += 64) {
#pragma unroll
        for (int i = 0; i < 4; i++) {
            int u = tid + i * 256;     // float4 unit 0..1023
            int r = u >> 4;
            int c = u & 15;
            float4 v = make_float4(0.f, 0.f, 0.f, 0.f);
            int row = rowBase + r;
            if (row < N) v = *(const float4*)(x + (size_t)row * 256 + k0 + c * 4);
            *(float4*)&xs[r][c * 4] = v;
        }
#pragma unroll
        for (int i = 0; i < 8; i++) {
            int u = tid + i * 256;     // 0..2047
            int r = u >> 5;
            int c = u & 31;
            *(float4*)&ws[r][c * 4] = *(const float4*)(W + (size_t)(k0 + r) * 128 + c * 4);
        }
        __syncthreads();
#pragma unroll
        for (int k = 0; k < 64; k++) {
            float xv[4];
#pragma unroll
            for (int i = 0; i < 4; i++) xv[i] = xs[ty * 4 + i][k];
            float4 w0 = *(float4*)&ws[k][tx * 4];
            float4 w1 = *(float4*)&ws[k][64 + tx * 4];
            float wv[8] = {w0.x, w0.y, w0.z, w0.w, w1.x, w1.y, w1.z, w1.w};
#pragma unroll
            for (int i = 0; i < 4; i++)
#pragma unroll
                for (int j = 0; j < 8; j++) acc[i][j] = fmaf(xv[i], wv[j], acc[i][j]);
        }
        __syncthreads();
    }
#pragma unroll
    for (int i = 0; i < 4; i++) {
        int row = rowBase + ty * 4 + i;
        if (row >= N) continue;
        float dv = dis[row];
        float d2 = dv * dv;
#pragma unroll
        for (int half = 0; half < 2; half++) {
            int colBase = half * 64 + tx * 4;
            float4 v = make_float4(acc[i][half * 4], acc[i][half * 4 + 1],
                                   acc[i][half * 4 + 2], acc[i][half * 4 + 3]);
            float4 a = make_float4(v.x * dv, v.y * dv, v.z * dv, v.w * dv);
            float4 b = make_float4(v.x * d2, v.y * d2, v.z * d2, v.w * d2);
            *(float4*)(A + (size_t)row * 128 + colBase) = a;
            *(float4*)(B + (size_t)row * 128 + colBase) = b;
        }
    }
}

// 32 lanes per node (float4/lane), 8 nodes per 256-thread block.
// MODE 0: B[node] += dis[node]*a
// MODE 1: v = relu(B[node] + dis[node]*a + b1); A[node] = v*dis; B[node] = v*dis^2
template <int MODE>
__global__ __launch_bounds__(256) void gather_kernel(const int* __restrict__ offs,
                                                     const int* __restrict__ adj,
                                                     const float* __restrict__ dis,
                                                     const float* __restrict__ b1,
                                                     const float* __restrict__ Ain,
                                                     float* __restrict__ Aout,
                                                     float* __restrict__ B, int N) {
    int tid = threadIdx.x;
    int lane = tid & 31;
    int node = blockIdx.x * 8 + (tid >> 5);
    if (node >= N) return;
    int beg = offs[node];
    int end = offs[node + 1];
    float4 a = make_float4(0.f, 0.f, 0.f, 0.f);
    int e = beg;
    for (; e + 3 < end; e += 4) {
        int s0 = adj[e], s1 = adj[e + 1], s2 = adj[e + 2], s3 = adj[e + 3];
        float4 v0 = ((const float4*)(Ain + (size_t)s0 * 128))[lane];
        float4 v1 = ((const float4*)(Ain + (size_t)s1 * 128))[lane];
        float4 v2 = ((const float4*)(Ain + (size_t)s2 * 128))[lane];
        float4 v3 = ((const float4*)(Ain + (size_t)s3 * 128))[lane];
        a.x += v0.x + v1.x + v2.x + v3.x;
        a.y += v0.y + v1.y + v2.y + v3.y;
        a.z += v0.z + v1.z + v2.z + v3.z;
        a.w += v0.w + v1.w + v2.w + v3.w;
    }
    for (; e < end; e++) {
        int s = adj[e];
        float4 v = ((const float4*)(Ain + (size_t)s * 128))[lane];
        a.x += v.x; a.y += v.y; a.z += v.z; a.w += v.w;
    }
    float dd = dis[node];
    float4* bp = (float4*)(B + (size_t)node * 128) + lane;
    float4 cur = *bp;
    if (MODE == 0) {
        cur.x += dd * a.x; cur.y += dd * a.y; cur.z += dd * a.z; cur.w += dd * a.w;
        *bp = cur;
    } else {
        float4 bb = ((const float4*)b1)[lane];
        float vx = fmaxf(cur.x + dd * a.x + bb.x, 0.f);
        float vy = fmaxf(cur.y + dd * a.y + bb.y, 0.f);
        float vz = fmaxf(cur.z + dd * a.z + bb.z, 0.f);
        float vw = fmaxf(cur.w + dd * a.w + bb.w, 0.f);
        float4* ap = (float4*)(Aout + (size_t)node * 128) + lane;
        *ap = make_float4(vx * dd, vy * dd, vz * dd, vw * dd);
        float d2 = dd * dd;
        *bp = make_float4(vx * d2, vy * d2, vz * d2, vw * d2);
    }
}

__device__ __forceinline__ int lbound_lds(const int* a, int n, int v) {
    int l = 0, r = n;
    while (l < r) { int m = (l + r) >> 1; if (a[m] < v) l = m + 1; else r = m; }
    return l;
}

// GEMM-tiled pool: 64-node tile per block.
// T = noise * exp(hagg@W4 + b4); segment-sum T (64) and hagg (128) by sorted batch.
__global__ __launch_bounds__(256) void pool2_kernel(const float* __restrict__ hagg,
                                                    const float* __restrict__ W4,
                                                    const float* __restrict__ b4,
                                                    const float* __restrict__ noise,
                                                    const int* __restrict__ batch,
                                                    float* __restrict__ pooledH,
                                                    float* __restrict__ pooledT,
                                                    int N) {
    __shared__ float xs[64][132];      // hagg tile (K=128, pad 4); later reused for T
    __shared__ float ws[128][64];      // W4
    __shared__ int sbatch[64];
    int tid = threadIdx.x;
    int rowBase = blockIdx.x * 64;
    int nrows = min(64, N - rowBase);

    // stage W4 (linear copy, 8192 f4)
#pragma unroll
    for (int i = 0; i < 32; i++)
        ((float4*)ws)[tid + i * 256] = ((const float4*)W4)[tid + i * 256];
    // stage hagg tile
#pragma unroll
    for (int i = 0; i < 8; i++) {
        int u = tid + i * 256;     // 0..2047 f4
        int r = u >> 5;
        int c = u & 31;
        int row = rowBase + r;
        float4 v = make_float4(0.f, 0.f, 0.f, 0.f);
        if (row < N) v = *(const float4*)(hagg + (size_t)row * 128 + c * 4);
        *(float4*)&xs[r][c * 4] = v;
    }
    if (tid < 64) {
        int row = rowBase + tid;
        sbatch[tid] = (row < N) ? batch[row] : 0x7fffffff;
    }
    __syncthreads();

    // GEMM: 4 rows x 4 cols per thread
    int tx = tid & 15;   // cols tx*4..+3
    int ty = tid >> 4;   // rows ty*4..+3
    float acc[4][4];
#pragma unroll
    for (int i = 0; i < 4; i++)
#pragma unroll
        for (int j = 0; j < 4; j++) acc[i][j] = 0.f;
#pragma unroll 8
    for (int k = 0; k < 128; k++) {
        float xv[4];
#pragma unroll
        for (int i = 0; i < 4; i++) xv[i] = xs[ty * 4 + i][k];
        float4 wv = *(float4*)&ws[k][tx * 4];
        float w[4] = {wv.x, wv.y, wv.z, wv.w};
#pragma unroll
        for (int i = 0; i < 4; i++)
#pragma unroll
            for (int j = 0; j < 4; j++) acc[i][j] = fmaf(xv[i], w[j], acc[i][j]);
    }
    __syncthreads();

    // segment range of this tile
    int g0 = sbatch[0];
    int g1 = (nrows > 0) ? sbatch[nrows - 1] : g0;

    // hagg column sums per segment (from xs, before overwrite)
    for (int g = g0; g <= g1; g++) {
        int lo = lbound_lds(sbatch, nrows, g);
        int hi = lbound_lds(sbatch, nrows, g + 1);
        if (hi > lo && tid < 128) {
            float s = 0.f;
            for (int r = lo; r < hi; r++) s += xs[r][tid];
            atomicAdd(&pooledH[g * 128 + tid], s);
        }
    }
    __syncthreads();

    // T = noise * exp(acc + b4) -> xs[row][col]
    float4 b4v = *(const float4*)(b4 + tx * 4);
    float bb[4] = {b4v.x, b4v.y, b4v.z, b4v.w};
#pragma unroll
    for (int i = 0; i < 4; i++) {
        int row = rowBase + ty * 4 + i;
        if (row < N) {
            float4 nz = *(const float4*)(noise + (size_t)row * 64 + tx * 4);
            float nv[4] = {nz.x, nz.y, nz.z, nz.w};
#pragma unroll
            for (int j = 0; j < 4; j++)
                xs[ty * 4 + i][tx * 4 + j] = nv[j] * expf(acc[i][j] + bb[j]);
        }
    }
    __syncthreads();

    // T column sums per segment
    for (int g = g0; g <= g1; g++) {
        int lo = lbound_lds(sbatch, nrows, g);
        int hi = lbound_lds(sbatch, nrows, g + 1);
        if (hi > lo && tid < 64) {
            float s = 0.f;
            for (int r = lo; r < hi; r++) s += xs[r][tid];
            atomicAdd(&pooledT[g * 64 + tid], s);
        }
    }
}

// pooled = (pooledH@W3 + cnt*b3 + pooledT)/max(cnt,1); logits = pooled@Wfc + bfc; log_softmax
__global__ __launch_bounds__(64) void final_kernel(const float* __restrict__ pooledH,
                                                   const float* __restrict__ pooledT,
                                                   const int* __restrict__ batch,
                                                   const float* __restrict__ W3,
                                                   const float* __restrict__ b3,
                                                   const float* __restrict__ Wfc,
                                                   const float* __restrict__ bfc,
                                                   float* __restrict__ out, int N) {
    int g = blockIdx.x;
    int f = threadIdx.x;  // 0..63
    __shared__ int seg[2];
    if (f < 2) {
        int target = g + f;
        int l = 0, r = N;
        while (l < r) { int m = (l + r) >> 1; if (batch[m] < target) l = m + 1; else r = m; }
        seg[f] = l;
    }
    __syncthreads();
    float cnt = (float)(seg[1] - seg[0]);
    float denom = fmaxf(cnt, 1.0f);
    float p = pooledT[g * 64 + f] + cnt * b3[f];
    const float* ph = pooledH + g * 128;
#pragma unroll
    for (int k = 0; k < 128; k++) p = fmaf(ph[k], W3[k * 64 + f], p);
    p /= denom;
    __shared__ float pl[64];
    __shared__ float lg[4];
    pl[f] = p;
    __syncthreads();
    if (f < 4) {
        float l = bfc[f];
#pragma unroll
        for (int k = 0; k < 64; k++) l = fmaf(pl[k], Wfc[k * 4 + f], l);
        lg[f] = l;
    }
    __syncthreads();
    if (f == 0) {
        float m = fmaxf(fmaxf(lg[0], lg[1]), fmaxf(lg[2], lg[3]));
        float s = expf(lg[0] - m) + expf(lg[1] - m) + expf(lg[2] - m) + expf(lg[3] - m);
        float lse = logf(s);
#pragma unroll
        for (int j = 0; j < 4; j++) out[g * 4 + j] = lg[j] - m - lse;
    }
}

extern "C" void kernel_launch(void* const* d_in, const int* in_sizes, int n_in,
                              void* d_out, int out_size, void* d_ws, size_t ws_size,
                              hipStream_t stream) {
    const float* x     = (const float*)d_in[0];
    const int*   ei    = (const int*)d_in[1];
    const int*   batch = (const int*)d_in[2];
    const float* W1    = (const float*)d_in[3];
    const float* b1    = (const float*)d_in[4];
    const float* W3    = (const float*)d_in[5];
    const float* b3    = (const float*)d_in[6];
    const float* W4    = (const float*)d_in[7];
    const float* b4    = (const float*)d_in[8];
    const float* Wfc   = (const float*)d_in[9];
    const float* bfc   = (const float*)d_in[10];
    const float* noise = (const float*)d_in[11];
    float* out = (float*)d_out;

    int N = in_sizes[0] / 256;
    int E = in_sizes[1] / 2;
    const int* src = ei;
    const int* dst = ei + E;

    // Workspace layout (floats first, then ints)
    float* A       = (float*)d_ws;                 // h0*dis, later h*dis      [N*128]
    float* B       = A + (size_t)N * 128;          // agg accumulators         [N*128]
    float* dis     = B + (size_t)N * 128;          // [N]
    float* pooledH = dis + N;                      // [512*128]
    float* pooledT = pooledH + 512 * 128;          // [512*64]
    int*   degi    = (int*)(pooledT + 512 * 64);   // [N]
    int*   offs    = degi + N;                     // [N+1]
    int*   cursor  = offs + N + 1;                 // [N]
    int*   adj     = cursor + N;                   // [E]

    hipMemsetAsync(degi, 0, (size_t)N * sizeof(int), stream);
    hipMemsetAsync(pooledH, 0, (size_t)(512 * 128 + 512 * 64) * sizeof(float), stream);

    // CSR build
    deg_kernel<<<(E + 255) / 256, 256, 0, stream>>>(dst, degi, E);
    dis_kernel<<<(N + 255) / 256, 256, 0, stream>>>(degi, dis, N);
    scan_kernel<<<1, 1024, 0, stream>>>(degi, offs, N);
    hipMemcpyAsync(cursor, offs, (size_t)N * sizeof(int), hipMemcpyDeviceToDevice, stream);
    fill_kernel<<<(E + 255) / 256, 256, 0, stream>>>(src, dst, cursor, adj, E);

    // Layer 1 GEMM: A = (x@W1)*dis, B = (x@W1)*dis^2
    gemm1_kernel<<<(N + 63) / 64, 256, 0, stream>>>(x, W1, dis, A, B, N);

    // gather1 + fused relu/bias/rescale: A = h*dis, B = h*dis^2
    gather_kernel<1><<<(N + 7) / 8, 256, 0, stream>>>(offs, adj, dis, b1, A, A, B, N);

    // gather2: B = hagg
    gather_kernel<0><<<(N + 7) / 8, 256, 0, stream>>>(offs, adj, dis, b1, A, A, B, N);

    // pooling (GEMM-tiled, segment-reduced)
    pool2_kernel<<<(N + 63) / 64, 256, 0, stream>>>(B, W4, b4, noise, batch,
                                                    pooledH, pooledT, N);

    final_kernel<<<512, 64, 0, stream>>>(pooledH, pooledT, batch, W3, b3, Wfc, bfc, out, N);
}

// Round 8
// 369.323 us; speedup vs baseline: 1.4486x; 1.3532x over previous
//
#include <hip/hip_runtime.h>
#include <hip/hip_bf16.h>
#include <cstdint>
#include <cmath>

// ---------------------------------------------------------------------------
// VGAE-style GCN forward, CSR-gather formulation:
//   deg(int) -> 3-phase parallel scan (fused dis + cursor init) -> CSR fill ->
//   gemm1: Abf = bf16((x@W1)*dis), B = (x@W1)*dis^2
//   gather<RELU>: h=relu(B + dis*sum Abf[src] + b1); Abf=bf16(h*dis), B=h*dis^2
//   gather<PLAIN>: B = B + dis*sum Abf[src]     (B = hagg, f32)
//   pool2: GEMM-tiled  T=noise*exp(hagg@W4+b4), segment-reduced by sorted batch
//   final: counts via binary search + pooled mean algebra + FC + log_softmax
// bf16 message table halves random-gather bytes; uint4 lanes halve VMEM insts.
// ---------------------------------------------------------------------------

__device__ __forceinline__ unsigned short f2bf(float f) {
    union { float f; unsigned u; } v; v.f = f;
    unsigned u = v.u;
    return (unsigned short)((u + 0x7fffu + ((u >> 16) & 1u)) >> 16);   // RNE
}
__device__ __forceinline__ float bf2f(unsigned b) {
    union { float f; unsigned u; } v; v.u = b << 16; return v.f;
}
__device__ __forceinline__ unsigned packbf(float lo, float hi) {
    return (unsigned)f2bf(lo) | ((unsigned)f2bf(hi) << 16);
}

__global__ __launch_bounds__(256) void deg_kernel(const int* __restrict__ dst,
                                                  int* __restrict__ deg, int E) {
    int e = blockIdx.x * 256 + threadIdx.x;
    if (e < E) atomicAdd(&deg[dst[e]], 1);
}

// --- 3-phase scan: 1024 elements per block (4 per thread) ---
__global__ __launch_bounds__(256) void scan1_kernel(const int* __restrict__ deg,
                                                    int* __restrict__ bsum, int N) {
    int t = threadIdx.x;
    int base = blockIdx.x * 1024 + t * 4;
    int s = 0;
    if (base + 3 < N) {
        int4 v = *(const int4*)(deg + base);
        s = v.x + v.y + v.z + v.w;
    } else {
        for (int i = 0; i < 4; i++) if (base + i < N) s += deg[base + i];
    }
    __shared__ int red[256];
    red[t] = s;
    __syncthreads();
    for (int off = 128; off > 0; off >>= 1) {
        if (t < off) red[t] += red[t + off];
        __syncthreads();
    }
    if (t == 0) bsum[blockIdx.x] = red[0];
}

__global__ __launch_bounds__(256) void scan2_kernel(int* __restrict__ bsum, int nb) {
    __shared__ int s[256];
    int t = threadIdx.x;
    s[t] = (t < nb) ? bsum[t] : 0;
    __syncthreads();
    for (int off = 1; off < 256; off <<= 1) {
        int u = (t >= off) ? s[t - off] : 0;
        __syncthreads();
        s[t] += u;
        __syncthreads();
    }
    if (t < nb) bsum[t] = (t == 0) ? 0 : s[t - 1];
}

// write offs (exclusive scan), cursor (= offs), dis = rsqrt(deg+1); offs[N] = E
__global__ __launch_bounds__(256) void scan3_kernel(const int* __restrict__ deg,
                                                    const int* __restrict__ bsum,
                                                    int* __restrict__ offs,
                                                    int* __restrict__ cursor,
                                                    float* __restrict__ dis,
                                                    int N, int E) {
    int t = threadIdx.x;
    int bid = blockIdx.x;
    int base = bid * 1024 + t * 4;
    int d[4] = {0, 0, 0, 0};
    if (base + 3 < N) {
        int4 v = *(const int4*)(deg + base);
        d[0] = v.x; d[1] = v.y; d[2] = v.z; d[3] = v.w;
    } else {
        for (int i = 0; i < 4; i++) if (base + i < N) d[i] = deg[base + i];
    }
    int s = d[0] + d[1] + d[2] + d[3];
    __shared__ int red[256];
    red[t] = s;
    __syncthreads();
    for (int off = 1; off < 256; off <<= 1) {
        int u = (t >= off) ? red[t - off] : 0;
        __syncthreads();
        red[t] += u;
        __syncthreads();
    }
    int run = bsum[bid] + ((t == 0) ? 0 : red[t - 1]);
#pragma unroll
    for (int i = 0; i < 4; i++) {
        int idx = base + i;
        if (idx < N) {
            offs[idx] = run;
            cursor[idx] = run;
            dis[idx] = rsqrtf((float)d[i] + 1.0f);
            run += d[i];
        }
    }
    if (bid == 0 && t == 0) offs[N] = E;
}

__global__ __launch_bounds__(256) void fill_kernel(const int* __restrict__ src,
                                                   const int* __restrict__ dst,
                                                   int* __restrict__ cursor,
                                                   int* __restrict__ adj, int E) {
    int e = blockIdx.x * 256 + threadIdx.x;
    if (e >= E) return;
    int pos = atomicAdd(&cursor[dst[e]], 1);
    adj[pos] = src[e];
}

// h0 = x @ W1 (M=N, Nc=128, K=256). Epilogue: Abf = bf16(h0*dis), B = h0*dis^2.
__global__ __launch_bounds__(256) void gemm1_kernel(const float* __restrict__ x,
                                                    const float* __restrict__ W,
                                                    const float* __restrict__ dis,
                                                    unsigned short* __restrict__ Abf,
                                                    float* __restrict__ B, int N) {
    __shared__ float xs[64][68];
    __shared__ float ws[64][128];
    int tid = threadIdx.x;
    int tx = tid & 15;
    int ty = tid >> 4;
    int rowBase = blockIdx.x * 64;

    float acc[4][8];
#pragma unroll
    for (int i = 0; i < 4; i++)
#pragma unroll
        for (int j = 0; j < 8; j++) acc[i][j] = 0.f;

    for (int k0 = 0; k0 < 256; k0 += 64) {
#pragma unroll
        for (int i = 0; i < 4; i++) {
            int u = tid + i * 256;
            int r = u >> 4;
            int c = u & 15;
            float4 v = make_float4(0.f, 0.f, 0.f, 0.f);
            int row = rowBase + r;
            if (row < N) v = *(const float4*)(x + (size_t)row * 256 + k0 + c * 4);
            *(float4*)&xs[r][c * 4] = v;
        }
#pragma unroll
        for (int i = 0; i < 8; i++) {
            int u = tid + i * 256;
            int r = u >> 5;
            int c = u & 31;
            *(float4*)&ws[r][c * 4] = *(const float4*)(W + (size_t)(k0 + r) * 128 + c * 4);
        }
        __syncthreads();
#pragma unroll
        for (int k = 0; k < 64; k++) {
            float xv[4];
#pragma unroll
            for (int i = 0; i < 4; i++) xv[i] = xs[ty * 4 + i][k];
            float4 w0 = *(float4*)&ws[k][tx * 4];
            float4 w1 = *(float4*)&ws[k][64 + tx * 4];
            float wv[8] = {w0.x, w0.y, w0.z, w0.w, w1.x, w1.y, w1.z, w1.w};
#pragma unroll
            for (int i = 0; i < 4; i++)
#pragma unroll
                for (int j = 0; j < 8; j++) acc[i][j] = fmaf(xv[i], wv[j], acc[i][j]);
        }
        __syncthreads();
    }
#pragma unroll
    for (int i = 0; i < 4; i++) {
        int row = rowBase + ty * 4 + i;
        if (row >= N) continue;
        float dv = dis[row];
        float d2 = dv * dv;
#pragma unroll
        for (int half = 0; half < 2; half++) {
            int colBase = half * 64 + tx * 4;
            float4 v = make_float4(acc[i][half * 4], acc[i][half * 4 + 1],
                                   acc[i][half * 4 + 2], acc[i][half * 4 + 3]);
            ushort4 a4;
            a4.x = f2bf(v.x * dv); a4.y = f2bf(v.y * dv);
            a4.z = f2bf(v.z * dv); a4.w = f2bf(v.w * dv);
            *(ushort4*)(Abf + (size_t)row * 128 + colBase) = a4;
            float4 b = make_float4(v.x * d2, v.y * d2, v.z * d2, v.w * d2);
            *(float4*)(B + (size_t)row * 128 + colBase) = b;
        }
    }
}

// 16 lanes per node (8 bf16 feats/lane via uint4 = 16B), 16 nodes per block.
// A 64-lane wave covers 4 rows per VMEM instruction (1 KiB).
// MODE 0: B[node] += dis[node]*a
// MODE 1: v = relu(B[node] + dis[node]*a + b1); Aout=bf16(v*dis); B=v*dis^2
template <int MODE>
__global__ __launch_bounds__(256) void gather_kernel(const int* __restrict__ offs,
                                                     const int* __restrict__ adj,
                                                     const float* __restrict__ dis,
                                                     const float* __restrict__ b1,
                                                     const unsigned short* __restrict__ Ain,
                                                     unsigned short* __restrict__ Aout,
                                                     float* __restrict__ B, int N) {
    int tid = threadIdx.x;
    int lane = tid & 15;                       // feats [lane*8, lane*8+8)
    int node = blockIdx.x * 16 + (tid >> 4);
    if (node >= N) return;
    int beg = offs[node];
    int end = offs[node + 1];
    float a[8];
#pragma unroll
    for (int j = 0; j < 8; j++) a[j] = 0.f;
    int e = beg;
    for (; e + 3 < end; e += 4) {
        int s0 = adj[e], s1 = adj[e + 1], s2 = adj[e + 2], s3 = adj[e + 3];
        uint4 r0 = ((const uint4*)(Ain + (size_t)s0 * 128))[lane];
        uint4 r1 = ((const uint4*)(Ain + (size_t)s1 * 128))[lane];
        uint4 r2 = ((const uint4*)(Ain + (size_t)s2 * 128))[lane];
        uint4 r3 = ((const uint4*)(Ain + (size_t)s3 * 128))[lane];
        a[0] += bf2f(r0.x & 0xffffu) + bf2f(r1.x & 0xffffu) + bf2f(r2.x & 0xffffu) + bf2f(r3.x & 0xffffu);
        a[1] += bf2f(r0.x >> 16)     + bf2f(r1.x >> 16)     + bf2f(r2.x >> 16)     + bf2f(r3.x >> 16);
        a[2] += bf2f(r0.y & 0xffffu) + bf2f(r1.y & 0xffffu) + bf2f(r2.y & 0xffffu) + bf2f(r3.y & 0xffffu);
        a[3] += bf2f(r0.y >> 16)     + bf2f(r1.y >> 16)     + bf2f(r2.y >> 16)     + bf2f(r3.y >> 16);
        a[4] += bf2f(r0.z & 0xffffu) + bf2f(r1.z & 0xffffu) + bf2f(r2.z & 0xffffu) + bf2f(r3.z & 0xffffu);
        a[5] += bf2f(r0.z >> 16)     + bf2f(r1.z >> 16)     + bf2f(r2.z >> 16)     + bf2f(r3.z >> 16);
        a[6] += bf2f(r0.w & 0xffffu) + bf2f(r1.w & 0xffffu) + bf2f(r2.w & 0xffffu) + bf2f(r3.w & 0xffffu);
        a[7] += bf2f(r0.w >> 16)     + bf2f(r1.w >> 16)     + bf2f(r2.w >> 16)     + bf2f(r3.w >> 16);
    }
    for (; e < end; e++) {
        int s = adj[e];
        uint4 r0 = ((const uint4*)(Ain + (size_t)s * 128))[lane];
        a[0] += bf2f(r0.x & 0xffffu);
        a[1] += bf2f(r0.x >> 16);
        a[2] += bf2f(r0.y & 0xffffu);
        a[3] += bf2f(r0.y >> 16);
        a[4] += bf2f(r0.z & 0xffffu);
        a[5] += bf2f(r0.z >> 16);
        a[6] += bf2f(r0.w & 0xffffu);
        a[7] += bf2f(r0.w >> 16);
    }
    float dd = dis[node];
    float* brow = B + (size_t)node * 128 + lane * 8;
    float4 cur0 = *(float4*)brow;
    float4 cur1 = *(float4*)(brow + 4);
    if (MODE == 0) {
        cur0.x += dd * a[0]; cur0.y += dd * a[1]; cur0.z += dd * a[2]; cur0.w += dd * a[3];
        cur1.x += dd * a[4]; cur1.y += dd * a[5]; cur1.z += dd * a[6]; cur1.w += dd * a[7];
        *(float4*)brow = cur0;
        *(float4*)(brow + 4) = cur1;
    } else {
        const float* b1p = b1 + lane * 8;
        float4 bb0 = *(const float4*)b1p;
        float4 bb1 = *(const float4*)(b1p + 4);
        float v0 = fmaxf(cur0.x + dd * a[0] + bb0.x, 0.f);
        float v1 = fmaxf(cur0.y + dd * a[1] + bb0.y, 0.f);
        float v2 = fmaxf(cur0.z + dd * a[2] + bb0.z, 0.f);
        float v3 = fmaxf(cur0.w + dd * a[3] + bb0.w, 0.f);
        float v4 = fmaxf(cur1.x + dd * a[4] + bb1.x, 0.f);
        float v5 = fmaxf(cur1.y + dd * a[5] + bb1.y, 0.f);
        float v6 = fmaxf(cur1.z + dd * a[6] + bb1.z, 0.f);
        float v7 = fmaxf(cur1.w + dd * a[7] + bb1.w, 0.f);
        uint4 w;
        w.x = packbf(v0 * dd, v1 * dd);
        w.y = packbf(v2 * dd, v3 * dd);
        w.z = packbf(v4 * dd, v5 * dd);
        w.w = packbf(v6 * dd, v7 * dd);
        *(uint4*)(Aout + (size_t)node * 128 + lane * 8) = w;
        float d2 = dd * dd;
        *(float4*)brow       = make_float4(v0 * d2, v1 * d2, v2 * d2, v3 * d2);
        *(float4*)(brow + 4) = make_float4(v4 * d2, v5 * d2, v6 * d2, v7 * d2);
    }
}

__device__ __forceinline__ int lbound_lds(const int* a, int n, int v) {
    int l = 0, r = n;
    while (l < r) { int m = (l + r) >> 1; if (a[m] < v) l = m + 1; else r = m; }
    return l;
}

// GEMM-tiled pool: 64-node tile per block.
__global__ __launch_bounds__(256) void pool2_kernel(const float* __restrict__ hagg,
                                                    const float* __restrict__ W4,
                                                    const float* __restrict__ b4,
                                                    const float* __restrict__ noise,
                                                    const int* __restrict__ batch,
                                                    float* __restrict__ pooledH,
                                                    float* __restrict__ pooledT,
                                                    int N) {
    __shared__ float xs[64][132];
    __shared__ float ws[128][64];
    __shared__ int sbatch[64];
    int tid = threadIdx.x;
    int rowBase = blockIdx.x * 64;
    int nrows = min(64, N - rowBase);

#pragma unroll
    for (int i = 0; i < 32; i++)
        ((float4*)ws)[tid + i * 256] = ((const float4*)W4)[tid + i * 256];
#pragma unroll
    for (int i = 0; i < 8; i++) {
        int u = tid + i * 256;
        int r = u >> 5;
        int c = u & 31;
        int row = rowBase + r;
        float4 v = make_float4(0.f, 0.f, 0.f, 0.f);
        if (row < N) v = *(const float4*)(hagg + (size_t)row * 128 + c * 4);
        *(float4*)&xs[r][c * 4] = v;
    }
    if (tid < 64) {
        int row = rowBase + tid;
        sbatch[tid] = (row < N) ? batch[row] : 0x7fffffff;
    }
    __syncthreads();

    int tx = tid & 15;
    int ty = tid >> 4;
    float acc[4][4];
#pragma unroll
    for (int i = 0; i < 4; i++)
#pragma unroll
        for (int j = 0; j < 4; j++) acc[i][j] = 0.f;
#pragma unroll 8
    for (int k = 0; k < 128; k++) {
        float xv[4];
#pragma unroll
        for (int i = 0; i < 4; i++) xv[i] = xs[ty * 4 + i][k];
        float4 wv = *(float4*)&ws[k][tx * 4];
        float w[4] = {wv.x, wv.y, wv.z, wv.w};
#pragma unroll
        for (int i = 0; i < 4; i++)
#pragma unroll
            for (int j = 0; j < 4; j++) acc[i][j] = fmaf(xv[i], w[j], acc[i][j]);
    }
    __syncthreads();

    int g0 = sbatch[0];
    int g1 = (nrows > 0) ? sbatch[nrows - 1] : g0;

    for (int g = g0; g <= g1; g++) {
        int lo = lbound_lds(sbatch, nrows, g);
        int hi = lbound_lds(sbatch, nrows, g + 1);
        if (hi > lo && tid < 128) {
            float s = 0.f;
            for (int r = lo; r < hi; r++) s += xs[r][tid];
            atomicAdd(&pooledH[g * 128 + tid], s);
        }
    }
    __syncthreads();

    float4 b4v = *(const float4*)(b4 + tx * 4);
    float bb[4] = {b4v.x, b4v.y, b4v.z, b4v.w};
#pragma unroll
    for (int i = 0; i < 4; i++) {
        int row = rowBase + ty * 4 + i;
        if (row < N) {
            float4 nz = *(const float4*)(noise + (size_t)row * 64 + tx * 4);
            float nv[4] = {nz.x, nz.y, nz.z, nz.w};
#pragma unroll
            for (int j = 0; j < 4; j++)
                xs[ty * 4 + i][tx * 4 + j] = nv[j] * expf(acc[i][j] + bb[j]);
        }
    }
    __syncthreads();

    for (int g = g0; g <= g1; g++) {
        int lo = lbound_lds(sbatch, nrows, g);
        int hi = lbound_lds(sbatch, nrows, g + 1);
        if (hi > lo && tid < 64) {
            float s = 0.f;
            for (int r = lo; r < hi; r++) s += xs[r][tid];
            atomicAdd(&pooledT[g * 64 + tid], s);
        }
    }
}

__global__ __launch_bounds__(64) void final_kernel(const float* __restrict__ pooledH,
                                                   const float* __restrict__ pooledT,
                                                   const int* __restrict__ batch,
                                                   const float* __restrict__ W3,
                                                   const float* __restrict__ b3,
                                                   const float* __restrict__ Wfc,
                                                   const float* __restrict__ bfc,
                                                   float* __restrict__ out, int N) {
    int g = blockIdx.x;
    int f = threadIdx.x;
    __shared__ int seg[2];
    if (f < 2) {
        int target = g + f;
        int l = 0, r = N;
        while (l < r) { int m = (l + r) >> 1; if (batch[m] < target) l = m + 1; else r = m; }
        seg[f] = l;
    }
    __syncthreads();
    float cnt = (float)(seg[1] - seg[0]);
    float denom = fmaxf(cnt, 1.0f);
    float p = pooledT[g * 64 + f] + cnt * b3[f];
    const float* ph = pooledH + g * 128;
#pragma unroll
    for (int k = 0; k < 128; k++) p = fmaf(ph[k], W3[k * 64 + f], p);
    p /= denom;
    __shared__ float pl[64];
    __shared__ float lg[4];
    pl[f] = p;
    __syncthreads();
    if (f < 4) {
        float l = bfc[f];
#pragma unroll
        for (int k = 0; k < 64; k++) l = fmaf(pl[k], Wfc[k * 4 + f], l);
        lg[f] = l;
    }
    __syncthreads();
    if (f == 0) {
        float m = fmaxf(fmaxf(lg[0], lg[1]), fmaxf(lg[2], lg[3]));
        float s = expf(lg[0] - m) + expf(lg[1] - m) + expf(lg[2] - m) + expf(lg[3] - m);
        float lse = logf(s);
#pragma unroll
        for (int j = 0; j < 4; j++) out[g * 4 + j] = lg[j] - m - lse;
    }
}

extern "C" void kernel_launch(void* const* d_in, const int* in_sizes, int n_in,
                              void* d_out, int out_size, void* d_ws, size_t ws_size,
                              hipStream_t stream) {
    const float* x     = (const float*)d_in[0];
    const int*   ei    = (const int*)d_in[1];
    const int*   batch = (const int*)d_in[2];
    const float* W1    = (const float*)d_in[3];
    const float* b1    = (const float*)d_in[4];
    const float* W3    = (const float*)d_in[5];
    const float* b3    = (const float*)d_in[6];
    const float* W4    = (const float*)d_in[7];
    const float* b4    = (const float*)d_in[8];
    const float* Wfc   = (const float*)d_in[9];
    const float* bfc   = (const float*)d_in[10];
    const float* noise = (const float*)d_in[11];
    float* out = (float*)d_out;

    int N = in_sizes[0] / 256;
    int E = in_sizes[1] / 2;
    const int* src = ei;
    const int* dst = ei + E;
    int nScanBlocks = (N + 1023) / 1024;

    // Workspace layout
    float* B = (float*)d_ws;                               // agg accum [N*128] f32
    unsigned short* Abf = (unsigned short*)(B + (size_t)N * 128);  // [N*128] bf16
    float* dis     = (float*)(Abf + (size_t)N * 128);      // [N]
    float* pooledH = dis + N;                              // [512*128]
    float* pooledT = pooledH + 512 * 128;                  // [512*64]
    int*   degi    = (int*)(pooledT + 512 * 64);           // [N]
    int*   offs    = degi + N;                             // [N+1]
    int*   cursor  = offs + N + 1;                         // [N]
    int*   bsum    = cursor + N;                           // [256]
    int*   adj     = bsum + 256;                           // [E]

    hipMemsetAsync(degi, 0, (size_t)N * sizeof(int), stream);
    hipMemsetAsync(pooledH, 0, (size_t)(512 * 128 + 512 * 64) * sizeof(float), stream);

    // CSR build
    deg_kernel<<<(E + 255) / 256, 256, 0, stream>>>(dst, degi, E);
    scan1_kernel<<<nScanBlocks, 256, 0, stream>>>(degi, bsum, N);
    scan2_kernel<<<1, 256, 0, stream>>>(bsum, nScanBlocks);
    scan3_kernel<<<nScanBlocks, 256, 0, stream>>>(degi, bsum, offs, cursor, dis, N, E);
    fill_kernel<<<(E + 255) / 256, 256, 0, stream>>>(src, dst, cursor, adj, E);

    // Layer 1 GEMM: Abf = bf16((x@W1)*dis), B = (x@W1)*dis^2
    gemm1_kernel<<<(N + 63) / 64, 256, 0, stream>>>(x, W1, dis, Abf, B, N);

    // gather1 + fused relu/bias/rescale: Abf = bf16(h*dis), B = h*dis^2
    gather_kernel<1><<<(N + 15) / 16, 256, 0, stream>>>(offs, adj, dis, b1, Abf, Abf, B, N);

    // gather2: B = hagg
    gather_kernel<0><<<(N + 15) / 16, 256, 0, stream>>>(offs, adj, dis, b1, Abf, Abf, B, N);

    // pooling (GEMM-tiled, segment-reduced)
    pool2_kernel<<<(N + 63) / 64, 256, 0, stream>>>(B, W4, b4, noise, batch,
                                                    pooledH, pooledT, N);

    final_kernel<<<512, 64, 0, stream>>>(pooledH, pooledT, batch, W3, b3, Wfc, bfc, out, N);
}

// Round 11
// 343.763 us; speedup vs baseline: 1.5563x; 1.0744x over previous
//
#include <hip/hip_runtime.h>
#include <hip/hip_bf16.h>
#include <cstdint>
#include <cmath>

// ---------------------------------------------------------------------------
// VGAE-style GCN forward, CSR-gather formulation:
//   deg(int) -> 3-phase parallel scan (fused dis + cursor init) -> CSR fill ->
//   wT = bf16(W1^T)  (one-time, L2-resident)
//   gemm1 (MFMA bf16): Abf = bf16((x@W1)*dis), B = (x@W1)*dis^2
//   gather<RELU>: h=relu(B + dis*sum Abf[src] + b1); Abf=bf16(h*dis), B=h*dis^2
//   gather<PLAIN>: B = B + dis*sum Abf[src]     (B = hagg, f32)
//   pool2: GEMM-tiled  T=noise*exp(hagg@W4+b4), segment-reduced by sorted batch
//   final: counts via binary search + pooled mean algebra + FC + log_softmax
// ---------------------------------------------------------------------------

typedef __attribute__((ext_vector_type(8))) short bf16x8;
typedef __attribute__((ext_vector_type(4))) float f32x4;

__device__ __forceinline__ unsigned short f2bf(float f) {
    union { float f; unsigned u; } v; v.f = f;
    unsigned u = v.u;
    return (unsigned short)((u + 0x7fffu + ((u >> 16) & 1u)) >> 16);   // RNE
}
__device__ __forceinline__ float bf2f(unsigned b) {
    union { float f; unsigned u; } v; v.u = b << 16; return v.f;
}
__device__ __forceinline__ unsigned packbf(float lo, float hi) {
    return (unsigned)f2bf(lo) | ((unsigned)f2bf(hi) << 16);
}

__global__ __launch_bounds__(256) void deg_kernel(const int* __restrict__ dst,
                                                  int* __restrict__ deg, int E) {
    int e = blockIdx.x * 256 + threadIdx.x;
    if (e < E) atomicAdd(&deg[dst[e]], 1);
}

// --- 3-phase scan: 1024 elements per block (4 per thread) ---
__global__ __launch_bounds__(256) void scan1_kernel(const int* __restrict__ deg,
                                                    int* __restrict__ bsum, int N) {
    int t = threadIdx.x;
    int base = blockIdx.x * 1024 + t * 4;
    int s = 0;
    if (base + 3 < N) {
        int4 v = *(const int4*)(deg + base);
        s = v.x + v.y + v.z + v.w;
    } else {
        for (int i = 0; i < 4; i++) if (base + i < N) s += deg[base + i];
    }
    __shared__ int red[256];
    red[t] = s;
    __syncthreads();
    for (int off = 128; off > 0; off >>= 1) {
        if (t < off) red[t] += red[t + off];
        __syncthreads();
    }
    if (t == 0) bsum[blockIdx.x] = red[0];
}

__global__ __launch_bounds__(256) void scan2_kernel(int* __restrict__ bsum, int nb) {
    __shared__ int s[256];
    int t = threadIdx.x;
    s[t] = (t < nb) ? bsum[t] : 0;
    __syncthreads();
    for (int off = 1; off < 256; off <<= 1) {
        int u = (t >= off) ? s[t - off] : 0;
        __syncthreads();
        s[t] += u;
        __syncthreads();
    }
    if (t < nb) bsum[t] = (t == 0) ? 0 : s[t - 1];
}

// write offs (exclusive scan), cursor (= offs), dis = rsqrt(deg+1); offs[N] = E
__global__ __launch_bounds__(256) void scan3_kernel(const int* __restrict__ deg,
                                                    const int* __restrict__ bsum,
                                                    int* __restrict__ offs,
                                                    int* __restrict__ cursor,
                                                    float* __restrict__ dis,
                                                    int N, int E) {
    int t = threadIdx.x;
    int bid = blockIdx.x;
    int base = bid * 1024 + t * 4;
    int d[4] = {0, 0, 0, 0};
    if (base + 3 < N) {
        int4 v = *(const int4*)(deg + base);
        d[0] = v.x; d[1] = v.y; d[2] = v.z; d[3] = v.w;
    } else {
        for (int i = 0; i < 4; i++) if (base + i < N) d[i] = deg[base + i];
    }
    int s = d[0] + d[1] + d[2] + d[3];
    __shared__ int red[256];
    red[t] = s;
    __syncthreads();
    for (int off = 1; off < 256; off <<= 1) {
        int u = (t >= off) ? red[t - off] : 0;
        __syncthreads();
        red[t] += u;
        __syncthreads();
    }
    int run = bsum[bid] + ((t == 0) ? 0 : red[t - 1]);
#pragma unroll
    for (int i = 0; i < 4; i++) {
        int idx = base + i;
        if (idx < N) {
            offs[idx] = run;
            cursor[idx] = run;
            dis[idx] = rsqrtf((float)d[i] + 1.0f);
            run += d[i];
        }
    }
    if (bid == 0 && t == 0) offs[N] = E;
}

__global__ __launch_bounds__(256) void fill_kernel(const int* __restrict__ src,
                                                   const int* __restrict__ dst,
                                                   int* __restrict__ cursor,
                                                   int* __restrict__ adj, int E) {
    int e = blockIdx.x * 256 + threadIdx.x;
    if (e >= E) return;
    int pos = atomicAdd(&cursor[dst[e]], 1);
    adj[pos] = src[e];
}

// one-time: wT[c][k] = bf16(W1[k][c]); W1 is [256][128]
__global__ __launch_bounds__(256) void wt_kernel(const float* __restrict__ W,
                                                 unsigned short* __restrict__ wT) {
    int idx = blockIdx.x * 256 + threadIdx.x;   // 0..32767
    if (idx < 32768) {
        int k = idx >> 7;
        int c = idx & 127;
        wT[c * 256 + k] = f2bf(W[idx]);
    }
}

// MFMA gemm1: h0 = x@W1 (M=N, Nc=128, K=256), bf16 inputs, f32 acc.
// A = x tile staged bf16 in LDS (whole K). B-frags read direct from wT (L2).
// Epilogue: Abf = bf16(h0*dis), B = h0*dis^2.
__global__ __launch_bounds__(256) void gemm1_mfma(const float* __restrict__ x,
                                                  const unsigned short* __restrict__ wT,
                                                  const float* __restrict__ dis,
                                                  unsigned short* __restrict__ Abf,
                                                  float* __restrict__ B, int N) {
    __shared__ unsigned short xs[64 * 264];   // [row][264], pad 8 -> 2-way bank alias
    int tid = threadIdx.x;
    int rowBase = blockIdx.x * 64;
    // stage x tile, f32 -> bf16
#pragma unroll
    for (int i = 0; i < 16; i++) {
        int u = tid + i * 256;     // float4 unit 0..4095
        int r = u >> 6;            // 64 f4 per row
        int c = u & 63;
        float4 v = make_float4(0.f, 0.f, 0.f, 0.f);
        int row = rowBase + r;
        if (row < N) v = *(const float4*)(x + (size_t)row * 256 + c * 4);
        ushort4 b;
        b.x = f2bf(v.x); b.y = f2bf(v.y); b.z = f2bf(v.z); b.w = f2bf(v.w);
        *(ushort4*)&xs[r * 264 + c * 4] = b;
    }
    __syncthreads();

    int wv = tid >> 6;     // wave 0..3 -> cols [wv*32, wv*32+32)
    int l = tid & 63;
    int lr = l & 15;       // A-row / B-col within tile
    int lk = l >> 4;       // k-slice quarter
    int colBase = wv * 32;

    f32x4 acc[4][2];
#pragma unroll
    for (int rt = 0; rt < 4; rt++)
#pragma unroll
        for (int ct = 0; ct < 2; ct++) acc[rt][ct] = (f32x4){0.f, 0.f, 0.f, 0.f};

    for (int ks = 0; ks < 8; ks++) {
        int kbase = ks * 32 + lk * 8;
        bf16x8 a[4], b[2];
#pragma unroll
        for (int rt = 0; rt < 4; rt++)
            a[rt] = *(const bf16x8*)&xs[(rt * 16 + lr) * 264 + kbase];
#pragma unroll
        for (int ct = 0; ct < 2; ct++)
            b[ct] = *(const bf16x8*)(wT + (size_t)(colBase + ct * 16 + lr) * 256 + kbase);
#pragma unroll
        for (int rt = 0; rt < 4; rt++)
#pragma unroll
            for (int ct = 0; ct < 2; ct++)
                acc[rt][ct] = __builtin_amdgcn_mfma_f32_16x16x32_bf16(
                    a[rt], b[ct], acc[rt][ct], 0, 0, 0);
    }

    // epilogue: D row = rt*16 + lk*4 + j, col = colBase + ct*16 + lr
#pragma unroll
    for (int rt = 0; rt < 4; rt++) {
#pragma unroll
        for (int j = 0; j < 4; j++) {
            int row = rowBase + rt * 16 + lk * 4 + j;
            if (row >= N) continue;
            float dv = dis[row];
            float d2 = dv * dv;
#pragma unroll
            for (int ct = 0; ct < 2; ct++) {
                int col = colBase + ct * 16 + lr;
                float v = acc[rt][ct][j];
                Abf[(size_t)row * 128 + col] = f2bf(v * dv);
                B[(size_t)row * 128 + col] = v * d2;
            }
        }
    }
}

// 16 lanes per node (8 bf16 feats/lane via uint4 = 16B), 16 nodes per block.
// MODE 0: B[node] += dis[node]*a
// MODE 1: v = relu(B[node] + dis[node]*a + b1); Aout=bf16(v*dis); B=v*dis^2
template <int MODE>
__global__ __launch_bounds__(256) void gather_kernel(const int* __restrict__ offs,
                                                     const int* __restrict__ adj,
                                                     const float* __restrict__ dis,
                                                     const float* __restrict__ b1,
                                                     const unsigned short* __restrict__ Ain,
                                                     unsigned short* __restrict__ Aout,
                                                     float* __restrict__ B, int N) {
    int tid = threadIdx.x;
    int lane = tid & 15;                       // feats [lane*8, lane*8+8)
    int node = blockIdx.x * 16 + (tid >> 4);
    if (node >= N) return;
    int beg = offs[node];
    int end = offs[node + 1];
    float a[8];
#pragma unroll
    for (int j = 0; j < 8; j++) a[j] = 0.f;
    int e = beg;
    for (; e + 3 < end; e += 4) {
        int s0 = adj[e], s1 = adj[e + 1], s2 = adj[e + 2], s3 = adj[e + 3];
        uint4 r0 = ((const uint4*)(Ain + (size_t)s0 * 128))[lane];
        uint4 r1 = ((const uint4*)(Ain + (size_t)s1 * 128))[lane];
        uint4 r2 = ((const uint4*)(Ain + (size_t)s2 * 128))[lane];
        uint4 r3 = ((const uint4*)(Ain + (size_t)s3 * 128))[lane];
        a[0] += bf2f(r0.x & 0xffffu) + bf2f(r1.x & 0xffffu) + bf2f(r2.x & 0xffffu) + bf2f(r3.x & 0xffffu);
        a[1] += bf2f(r0.x >> 16)     + bf2f(r1.x >> 16)     + bf2f(r2.x >> 16)     + bf2f(r3.x >> 16);
        a[2] += bf2f(r0.y & 0xffffu) + bf2f(r1.y & 0xffffu) + bf2f(r2.y & 0xffffu) + bf2f(r3.y & 0xffffu);
        a[3] += bf2f(r0.y >> 16)     + bf2f(r1.y >> 16)     + bf2f(r2.y >> 16)     + bf2f(r3.y >> 16);
        a[4] += bf2f(r0.z & 0xffffu) + bf2f(r1.z & 0xffffu) + bf2f(r2.z & 0xffffu) + bf2f(r3.z & 0xffffu);
        a[5] += bf2f(r0.z >> 16)     + bf2f(r1.z >> 16)     + bf2f(r2.z >> 16)     + bf2f(r3.z >> 16);
        a[6] += bf2f(r0.w & 0xffffu) + bf2f(r1.w & 0xffffu) + bf2f(r2.w & 0xffffu) + bf2f(r3.w & 0xffffu);
        a[7] += bf2f(r0.w >> 16)     + bf2f(r1.w >> 16)     + bf2f(r2.w >> 16)     + bf2f(r3.w >> 16);
    }
    for (; e < end; e++) {
        int s = adj[e];
        uint4 r0 = ((const uint4*)(Ain + (size_t)s * 128))[lane];
        a[0] += bf2f(r0.x & 0xffffu);
        a[1] += bf2f(r0.x >> 16);
        a[2] += bf2f(r0.y & 0xffffu);
        a[3] += bf2f(r0.y >> 16);
        a[4] += bf2f(r0.z & 0xffffu);
        a[5] += bf2f(r0.z >> 16);
        a[6] += bf2f(r0.w & 0xffffu);
        a[7] += bf2f(r0.w >> 16);
    }
    float dd = dis[node];
    float* brow = B + (size_t)node * 128 + lane * 8;
    float4 cur0 = *(float4*)brow;
    float4 cur1 = *(float4*)(brow + 4);
    if (MODE == 0) {
        cur0.x += dd * a[0]; cur0.y += dd * a[1]; cur0.z += dd * a[2]; cur0.w += dd * a[3];
        cur1.x += dd * a[4]; cur1.y += dd * a[5]; cur1.z += dd * a[6]; cur1.w += dd * a[7];
        *(float4*)brow = cur0;
        *(float4*)(brow + 4) = cur1;
    } else {
        const float* b1p = b1 + lane * 8;
        float4 bb0 = *(const float4*)b1p;
        float4 bb1 = *(const float4*)(b1p + 4);
        float v0 = fmaxf(cur0.x + dd * a[0] + bb0.x, 0.f);
        float v1 = fmaxf(cur0.y + dd * a[1] + bb0.y, 0.f);
        float v2 = fmaxf(cur0.z + dd * a[2] + bb0.z, 0.f);
        float v3 = fmaxf(cur0.w + dd * a[3] + bb0.w, 0.f);
        float v4 = fmaxf(cur1.x + dd * a[4] + bb1.x, 0.f);
        float v5 = fmaxf(cur1.y + dd * a[5] + bb1.y, 0.f);
        float v6 = fmaxf(cur1.z + dd * a[6] + bb1.z, 0.f);
        float v7 = fmaxf(cur1.w + dd * a[7] + bb1.w, 0.f);
        uint4 w;
        w.x = packbf(v0 * dd, v1 * dd);
        w.y = packbf(v2 * dd, v3 * dd);
        w.z = packbf(v4 * dd, v5 * dd);
        w.w = packbf(v6 * dd, v7 * dd);
        *(uint4*)(Aout + (size_t)node * 128 + lane * 8) = w;
        float d2 = dd * dd;
        *(float4*)brow       = make_float4(v0 * d2, v1 * d2, v2 * d2, v3 * d2);
        *(float4*)(brow + 4) = make_float4(v4 * d2, v5 * d2, v6 * d2, v7 * d2);
    }
}

__device__ __forceinline__ int lbound_lds(const int* a, int n, int v) {
    int l = 0, r = n;
    while (l < r) { int m = (l + r) >> 1; if (a[m] < v) l = m + 1; else r = m; }
    return l;
}

// GEMM-tiled pool: 64-node tile per block.
__global__ __launch_bounds__(256) void pool2_kernel(const float* __restrict__ hagg,
                                                    const float* __restrict__ W4,
                                                    const float* __restrict__ b4,
                                                    const float* __restrict__ noise,
                                                    const int* __restrict__ batch,
                                                    float* __restrict__ pooledH,
                                                    float* __restrict__ pooledT,
                                                    int N) {
    __shared__ float xs[64][132];
    __shared__ float ws[128][64];
    __shared__ int sbatch[64];
    int tid = threadIdx.x;
    int rowBase = blockIdx.x * 64;
    int nrows = min(64, N - rowBase);

#pragma unroll
    for (int i = 0; i < 32; i++)
        ((float4*)ws)[tid + i * 256] = ((const float4*)W4)[tid + i * 256];
#pragma unroll
    for (int i = 0; i < 8; i++) {
        int u = tid + i * 256;
        int r = u >> 5;
        int c = u & 31;
        int row = rowBase + r;
        float4 v = make_float4(0.f, 0.f, 0.f, 0.f);
        if (row < N) v = *(const float4*)(hagg + (size_t)row * 128 + c * 4);
        *(float4*)&xs[r][c * 4] = v;
    }
    if (tid < 64) {
        int row = rowBase + tid;
        sbatch[tid] = (row < N) ? batch[row] : 0x7fffffff;
    }
    __syncthreads();

    int tx = tid & 15;
    int ty = tid >> 4;
    float acc[4][4];
#pragma unroll
    for (int i = 0; i < 4; i++)
#pragma unroll
        for (int j = 0; j < 4; j++) acc[i][j] = 0.f;
#pragma unroll 8
    for (int k = 0; k < 128; k++) {
        float xv[4];
#pragma unroll
        for (int i = 0; i < 4; i++) xv[i] = xs[ty * 4 + i][k];
        float4 wv = *(float4*)&ws[k][tx * 4];
        float w[4] = {wv.x, wv.y, wv.z, wv.w};
#pragma unroll
        for (int i = 0; i < 4; i++)
#pragma unroll
            for (int j = 0; j < 4; j++) acc[i][j] = fmaf(xv[i], w[j], acc[i][j]);
    }
    __syncthreads();

    int g0 = sbatch[0];
    int g1 = (nrows > 0) ? sbatch[nrows - 1] : g0;

    for (int g = g0; g <= g1; g++) {
        int lo = lbound_lds(sbatch, nrows, g);
        int hi = lbound_lds(sbatch, nrows, g + 1);
        if (hi > lo && tid < 128) {
            float s = 0.f;
            for (int r = lo; r < hi; r++) s += xs[r][tid];
            atomicAdd(&pooledH[g * 128 + tid], s);
        }
    }
    __syncthreads();

    float4 b4v = *(const float4*)(b4 + tx * 4);
    float bb[4] = {b4v.x, b4v.y, b4v.z, b4v.w};
#pragma unroll
    for (int i = 0; i < 4; i++) {
        int row = rowBase + ty * 4 + i;
        if (row < N) {
            float4 nz = *(const float4*)(noise + (size_t)row * 64 + tx * 4);
            float nv[4] = {nz.x, nz.y, nz.z, nz.w};
#pragma unroll
            for (int j = 0; j < 4; j++)
                xs[ty * 4 + i][tx * 4 + j] = nv[j] * expf(acc[i][j] + bb[j]);
        }
    }
    __syncthreads();

    for (int g = g0; g <= g1; g++) {
        int lo = lbound_lds(sbatch, nrows, g);
        int hi = lbound_lds(sbatch, nrows, g + 1);
        if (hi > lo && tid < 64) {
            float s = 0.f;
            for (int r = lo; r < hi; r++) s += xs[r][tid];
            atomicAdd(&pooledT[g * 64 + tid], s);
        }
    }
}

__global__ __launch_bounds__(64) void final_kernel(const float* __restrict__ pooledH,
                                                   const float* __restrict__ pooledT,
                                                   const int* __restrict__ batch,
                                                   const float* __restrict__ W3,
                                                   const float* __restrict__ b3,
                                                   const float* __restrict__ Wfc,
                                                   const float* __restrict__ bfc,
                                                   float* __restrict__ out, int N) {
    int g = blockIdx.x;
    int f = threadIdx.x;
    __shared__ int seg[2];
    if (f < 2) {
        int target = g + f;
        int l = 0, r = N;
        while (l < r) { int m = (l + r) >> 1; if (batch[m] < target) l = m + 1; else r = m; }
        seg[f] = l;
    }
    __syncthreads();
    float cnt = (float)(seg[1] - seg[0]);
    float denom = fmaxf(cnt, 1.0f);
    float p = pooledT[g * 64 + f] + cnt * b3[f];
    const float* ph = pooledH + g * 128;
#pragma unroll
    for (int k = 0; k < 128; k++) p = fmaf(ph[k], W3[k * 64 + f], p);
    p /= denom;
    __shared__ float pl[64];
    __shared__ float lg[4];
    pl[f] = p;
    __syncthreads();
    if (f < 4) {
        float l = bfc[f];
#pragma unroll
        for (int k = 0; k < 64; k++) l = fmaf(pl[k], Wfc[k * 4 + f], l);
        lg[f] = l;
    }
    __syncthreads();
    if (f == 0) {
        float m = fmaxf(fmaxf(lg[0], lg[1]), fmaxf(lg[2], lg[3]));
        float s = expf(lg[0] - m) + expf(lg[1] - m) + expf(lg[2] - m) + expf(lg[3] - m);
        float lse = logf(s);
#pragma unroll
        for (int j = 0; j < 4; j++) out[g * 4 + j] = lg[j] - m - lse;
    }
}

extern "C" void kernel_launch(void* const* d_in, const int* in_sizes, int n_in,
                              void* d_out, int out_size, void* d_ws, size_t ws_size,
                              hipStream_t stream) {
    const float* x     = (const float*)d_in[0];
    const int*   ei    = (const int*)d_in[1];
    const int*   batch = (const int*)d_in[2];
    const float* W1    = (const float*)d_in[3];
    const float* b1    = (const float*)d_in[4];
    const float* W3    = (const float*)d_in[5];
    const float* b3    = (const float*)d_in[6];
    const float* W4    = (const float*)d_in[7];
    const float* b4    = (const float*)d_in[8];
    const float* Wfc   = (const float*)d_in[9];
    const float* bfc   = (const float*)d_in[10];
    const float* noise = (const float*)d_in[11];
    float* out = (float*)d_out;

    int N = in_sizes[0] / 256;
    int E = in_sizes[1] / 2;
    const int* src = ei;
    const int* dst = ei + E;
    int nScanBlocks = (N + 1023) / 1024;

    // Workspace layout
    float* B = (float*)d_ws;                               // agg accum [N*128] f32
    unsigned short* Abf = (unsigned short*)(B + (size_t)N * 128);  // [N*128] bf16
    unsigned short* wT  = Abf + (size_t)N * 128;           // [128*256] bf16
    float* dis     = (float*)(wT + 128 * 256);             // [N]
    float* pooledH = dis + N;                              // [512*128]
    float* pooledT = pooledH + 512 * 128;                  // [512*64]
    int*   degi    = (int*)(pooledT + 512 * 64);           // [N]
    int*   offs    = degi + N;                             // [N+1]
    int*   cursor  = offs + N + 1;                         // [N]
    int*   bsum    = cursor + N;                           // [256]
    int*   adj     = bsum + 256;                           // [E]

    hipMemsetAsync(degi, 0, (size_t)N * sizeof(int), stream);
    hipMemsetAsync(pooledH, 0, (size_t)(512 * 128 + 512 * 64) * sizeof(float), stream);

    // CSR build + one-time W1 transpose
    deg_kernel<<<(E + 255) / 256, 256, 0, stream>>>(dst, degi, E);
    scan1_kernel<<<nScanBlocks, 256, 0, stream>>>(degi, bsum, N);
    scan2_kernel<<<1, 256, 0, stream>>>(bsum, nScanBlocks);
    scan3_kernel<<<nScanBlocks, 256, 0, stream>>>(degi, bsum, offs, cursor, dis, N, E);
    fill_kernel<<<(E + 255) / 256, 256, 0, stream>>>(src, dst, cursor, adj, E);
    wt_kernel<<<128, 256, 0, stream>>>(W1, wT);

    // Layer 1 GEMM (MFMA): Abf = bf16((x@W1)*dis), B = (x@W1)*dis^2
    gemm1_mfma<<<(N + 63) / 64, 256, 0, stream>>>(x, wT, dis, Abf, B, N);

    // gather1 + fused relu/bias/rescale: Abf = bf16(h*dis), B = h*dis^2
    gather_kernel<1><<<(N + 15) / 16, 256, 0, stream>>>(offs, adj, dis, b1, Abf, Abf, B, N);

    // gather2: B = hagg
    gather_kernel<0><<<(N + 15) / 16, 256, 0, stream>>>(offs, adj, dis, b1, Abf, Abf, B, N);

    // pooling (GEMM-tiled, segment-reduced)
    pool2_kernel<<<(N + 63) / 64, 256, 0, stream>>>(B, W4, b4, noise, batch,
                                                    pooledH, pooledT, N);

    final_kernel<<<512, 64, 0, stream>>>(pooledH, pooledT, batch, W3, b3, Wfc, bfc, out, N);
}